// Round 1
// baseline (447.372 us; speedup 1.0000x reference)
//
#include <hip/hip_runtime.h>
#include <math.h>

// Problem constants
#define BB   128
#define CC   5
#define PP   5
#define LL   5
#define DD   128
#define NSEQ (BB*CC)      // 640
#define GATES 512         // 4*DD
#define IN0  384          // 3*DD

__device__ __forceinline__ float sigf(float x){ return 1.0f/(1.0f+__expf(-x)); }
__device__ __forceinline__ float tanhfast(float x){ return 1.0f - 2.0f/(__expf(2.0f*x)+1.0f); }

// ---- prep: transpose weights [p][g][k] -> [p][k][g] --------------------------
__global__ void transpose_w(const float* __restrict__ src, float* __restrict__ dst,
                            int G, int K){
    int id = blockIdx.x*256 + threadIdx.x;
    int total = PP*G*K;
    if (id >= total) return;
    int p = id/(G*K);
    int r = id%(G*K);
    int k = r / G;
    int g = r % G;
    // dst[p][k][g] = src[p][g][k]
    dst[id] = src[(size_t)(p*G + g)*K + k];
}

__global__ void bias_prep(const float* __restrict__ bih0, const float* __restrict__ bhh0,
                          const float* __restrict__ bih1, const float* __restrict__ bhh1,
                          float* __restrict__ b0, float* __restrict__ b1c){
    int id = blockIdx.x*256 + threadIdx.x;
    if (id < PP*GATES){
        b0[id] = bih0[id] + bhh0[id];
    } else if (id < 2*PP*GATES){
        int j = id - PP*GATES;
        b1c[j] = bih1[j] + bhh1[j];
    }
}

// ---- gather + concat: X[p][t][n][384] (only t<=p written) --------------------
__global__ void gather_x(const int* __restrict__ user_index,
                         const int* __restrict__ tpath, const int* __restrict__ ttype,
                         const int* __restrict__ trel,
                         const float* __restrict__ entity_emb, const float* __restrict__ relation_emb,
                         const float* __restrict__ user_emb, const float* __restrict__ news_emb,
                         const float* __restrict__ type_emb,
                         float* __restrict__ X){
    int id = blockIdx.x*256 + threadIdx.x;       // over 25*640*96 float4 slots
    if (id >= PP*LL*NSEQ*96) return;
    int pt  = id / (NSEQ*96);
    int rem = id % (NSEQ*96);
    int n = rem / 96;
    int q = rem % 96;
    int p = pt / LL, t = pt % LL;
    if (t > p) return;                           // only needed timesteps
    int b = n / CC, c = n % CC;
    int u = user_index[b];
    int base = ((u*CC + c)*PP + p)*LL + t;
    float4 v;
    if (q < 32){
        int pathi = tpath[base];
        int ty    = ttype[base];
        const float* e = (ty==0) ? user_emb : (ty==1) ? news_emb : entity_emb;
        v = *(const float4*)(e + (size_t)pathi*DD + q*4);
    } else if (q < 64){
        int ty = ttype[base];
        v = *(const float4*)(type_emb + (size_t)ty*DD + (q-32)*4);
    } else {
        int rel = trel[base];
        v = *(const float4*)(relation_emb + (size_t)rel*DD + (q-64)*4);
    }
    *(float4*)(X + (size_t)(pt*NSEQ + n)*IN0 + q*4) = v;
}

// ---- GEMM: Gih0[p][t][n][512] = X[p][t][n][:] @ Wih0T[p] + b0[p] -------------
#define K3_ROWS 16
#define XPAD 20
__global__ __launch_bounds__(256) void gemm_ih0(const float* __restrict__ X,
                          const float* __restrict__ WihT,  // [5][384][512]
                          const float* __restrict__ b0,    // [5][512]
                          float* __restrict__ Gout){       // [5][5][640][512]
    __shared__ float xs[IN0*XPAD];
    int bx = blockIdx.x;
    int p   = bx / 200;
    int rem = bx % 200;
    int t   = rem / 40;
    int nt  = rem % 40;
    if (t > p) return;
    int n0 = nt*K3_ROWS;
    int pt = p*LL + t;
    const float* Xblk = X + (size_t)(pt*NSEQ + n0)*IN0;
    // stage A tile transposed: xs[k][r], pad 20 keeps float4 reads 16B-aligned
    for (int i = threadIdx.x; i < K3_ROWS*IN0; i += 256){
        int r = i / IN0, k = i % IN0;
        xs[k*XPAD + r] = Xblk[(size_t)r*IN0 + k];
    }
    __syncthreads();
    int g0 = threadIdx.x*2;
    float acc0[K3_ROWS], acc1[K3_ROWS];
    float bb0 = b0[p*GATES + g0], bb1 = b0[p*GATES + g0 + 1];
    #pragma unroll
    for (int r=0;r<K3_ROWS;r++){ acc0[r]=bb0; acc1[r]=bb1; }
    const float* Wp = WihT + (size_t)p*IN0*GATES;
    #pragma unroll 4
    for (int k=0;k<IN0;k++){
        float2 w = *(const float2*)(Wp + (size_t)k*GATES + g0);
        const float* xk = xs + k*XPAD;
        float xv[K3_ROWS];
        *(float4*)&xv[0]  = *(const float4*)(xk);
        *(float4*)&xv[4]  = *(const float4*)(xk+4);
        *(float4*)&xv[8]  = *(const float4*)(xk+8);
        *(float4*)&xv[12] = *(const float4*)(xk+12);
        #pragma unroll
        for (int r=0;r<K3_ROWS;r++){
            acc0[r] = fmaf(xv[r], w.x, acc0[r]);
            acc1[r] = fmaf(xv[r], w.y, acc1[r]);
        }
    }
    float* Op = Gout + (size_t)(pt*NSEQ + n0)*GATES;
    #pragma unroll
    for (int r=0;r<K3_ROWS;r++){
        float2 st; st.x = acc0[r]; st.y = acc1[r];
        *(float2*)(Op + (size_t)r*GATES + g0) = st;
    }
}

// ---- fused 2-layer LSTM + scoring MLP ---------------------------------------
#define LROWS 8
__global__ __launch_bounds__(256) void lstm_kernel(
    const float* __restrict__ G0,      // [25][640][512] precomputed ih0 + bias
    const float* __restrict__ Whh0T,   // [5][128][512]
    const float* __restrict__ Wih1T,   // [5][128][512]
    const float* __restrict__ Whh1T,   // [5][128][512]
    const float* __restrict__ b1c,     // [5][512]
    const float* __restrict__ W1, const float* __restrict__ b1v,
    const float* __restrict__ W2, const float* __restrict__ b2v,
    float* __restrict__ psum){
    __shared__ float gs[GATES*LROWS];  // 16 KB gate staging
    __shared__ float h0T[DD*LROWS];    // h stored transposed: [j][r]
    __shared__ float h1T[DD*LROWS];
    int bx = blockIdx.x;
    int p  = bx / (NSEQ/LROWS);
    int nt = bx % (NSEQ/LROWS);
    int n0 = nt*LROWS;
    int tid = threadIdx.x;
    int g0 = tid*2;
    const float* W0p = Whh0T + (size_t)p*DD*GATES;
    const float* W1p = Wih1T + (size_t)p*DD*GATES;
    const float* W2p = Whh1T + (size_t)p*DD*GATES;
    float c0reg[4], c1reg[4];          // cell state: thread owns items tid+s*256
    float bbx = b1c[p*GATES + g0], bby = b1c[p*GATES + g0 + 1];

    for (int t=0; t<=p; t++){
        // ---- layer 0: G = Gih0 (+ h0 @ Whh0T) ----
        float a0[LROWS], a1[LROWS];
        const float* Gptr = G0 + (size_t)((p*LL + t)*NSEQ + n0)*GATES;
        #pragma unroll
        for (int r=0;r<LROWS;r++){
            float2 g = *(const float2*)(Gptr + (size_t)r*GATES + g0);
            a0[r]=g.x; a1[r]=g.y;
        }
        if (t > 0){
            #pragma unroll 2
            for (int k=0;k<DD;k++){
                float2 w = *(const float2*)(W0p + (size_t)k*GATES + g0);
                float xv[LROWS];
                *(float4*)&xv[0] = *(const float4*)(h0T + k*LROWS);
                *(float4*)&xv[4] = *(const float4*)(h0T + k*LROWS + 4);
                #pragma unroll
                for (int r=0;r<LROWS;r++){
                    a0[r] = fmaf(xv[r], w.x, a0[r]);
                    a1[r] = fmaf(xv[r], w.y, a1[r]);
                }
            }
        }
        #pragma unroll
        for (int r=0;r<LROWS;r++){ gs[g0*LROWS+r]=a0[r]; gs[(g0+1)*LROWS+r]=a1[r]; }
        __syncthreads();
        // gates layer 0 (i,f,g,o)
        #pragma unroll
        for (int s=0;s<4;s++){
            int item = tid + s*256;    // item = j*8 + r
            float gi = gs[item], gf = gs[item+1024], gg = gs[item+2048], go = gs[item+3072];
            float cprev = (t>0) ? c0reg[s] : 0.0f;
            float c = sigf(gf)*cprev + sigf(gi)*tanhfast(gg);
            c0reg[s] = c;
            h0T[item] = sigf(go)*tanhfast(c);
        }
        __syncthreads();
        // ---- layer 1: G = h0 @ Wih1T + b1c (+ h1 @ Whh1T) ----
        #pragma unroll
        for (int r=0;r<LROWS;r++){ a0[r]=bbx; a1[r]=bby; }
        #pragma unroll 2
        for (int k=0;k<DD;k++){
            float2 w = *(const float2*)(W1p + (size_t)k*GATES + g0);
            float xv[LROWS];
            *(float4*)&xv[0] = *(const float4*)(h0T + k*LROWS);
            *(float4*)&xv[4] = *(const float4*)(h0T + k*LROWS + 4);
            #pragma unroll
            for (int r=0;r<LROWS;r++){
                a0[r] = fmaf(xv[r], w.x, a0[r]);
                a1[r] = fmaf(xv[r], w.y, a1[r]);
            }
        }
        if (t > 0){
            #pragma unroll 2
            for (int k=0;k<DD;k++){
                float2 w = *(const float2*)(W2p + (size_t)k*GATES + g0);
                float xv[LROWS];
                *(float4*)&xv[0] = *(const float4*)(h1T + k*LROWS);
                *(float4*)&xv[4] = *(const float4*)(h1T + k*LROWS + 4);
                #pragma unroll
                for (int r=0;r<LROWS;r++){
                    a0[r] = fmaf(xv[r], w.x, a0[r]);
                    a1[r] = fmaf(xv[r], w.y, a1[r]);
                }
            }
        }
        #pragma unroll
        for (int r=0;r<LROWS;r++){ gs[g0*LROWS+r]=a0[r]; gs[(g0+1)*LROWS+r]=a1[r]; }
        __syncthreads();
        // gates layer 1
        #pragma unroll
        for (int s=0;s<4;s++){
            int item = tid + s*256;
            float gi = gs[item], gf = gs[item+1024], gg = gs[item+2048], go = gs[item+3072];
            float cprev = (t>0) ? c1reg[s] : 0.0f;
            float c = sigf(gf)*cprev + sigf(gi)*tanhfast(gg);
            c1reg[s] = c;
            h1T[item] = sigf(go)*tanhfast(c);
        }
        __syncthreads();
    }
    // ---- scoring MLP on h1 at t=p: sigmoid(relu(h1@W1.T+b1)@W2.T+b2) ----
    if (tid < LROWS*16){
        int r = tid & (LROWS-1), h = tid >> 3;
        float acc = b1v[h];
        #pragma unroll 4
        for (int k=0;k<DD;k++) acc = fmaf(h1T[k*LROWS + r], W1[h*DD + k], acc);
        gs[r*16 + h] = fmaxf(acc, 0.0f);
    }
    __syncthreads();
    if (tid < LROWS){
        float s = b2v[0];
        #pragma unroll
        for (int h=0;h<16;h++) s = fmaf(gs[tid*16 + h], W2[h], s);
        atomicAdd(&psum[n0 + tid], 0.2f*sigf(s));
    }
}

// ---- final: emb_score + running mean ----------------------------------------
__global__ void final_kernel(const int* __restrict__ cand, const int* __restrict__ user_index,
                             const float* __restrict__ news_emb, const float* __restrict__ user_emb,
                             const float* __restrict__ psum, float* __restrict__ out){
    int b = blockIdx.x;
    int lane = threadIdx.x; // 64
    int u = user_index[b];
    const float* ue = user_emb + (size_t)u*DD;
    float cum = 0.0f;
    for (int c=0;c<CC;c++){
        int nb = cand[b*CC + c];
        const float* ne = news_emb + (size_t)nb*DD;
        float v = ne[lane]*ue[lane] + ne[lane+64]*ue[lane+64];
        #pragma unroll
        for (int off=32; off; off>>=1) v += __shfl_down(v, off, 64);
        if (lane == 0){
            cum += psum[b*CC + c];
            out[b*CC + c] = sigf(v) + cum/(float)(c+1);
        }
    }
}

extern "C" void kernel_launch(void* const* d_in, const int* in_sizes, int n_in,
                              void* d_out, int out_size, void* d_ws, size_t ws_size,
                              hipStream_t stream){
    const int* cand        = (const int*)d_in[0];
    const int* uidx        = (const int*)d_in[1];
    const int* tpath       = (const int*)d_in[2];
    const int* ttype       = (const int*)d_in[3];
    const int* trel        = (const int*)d_in[4];
    const float* entity_emb   = (const float*)d_in[5];
    const float* relation_emb = (const float*)d_in[6];
    const float* user_emb     = (const float*)d_in[7];
    const float* news_emb     = (const float*)d_in[8];
    const float* type_emb     = (const float*)d_in[9];
    const float* Wih0 = (const float*)d_in[10];
    const float* Whh0 = (const float*)d_in[11];
    const float* bih0 = (const float*)d_in[12];
    const float* bhh0 = (const float*)d_in[13];
    const float* Wih1 = (const float*)d_in[14];
    const float* Whh1 = (const float*)d_in[15];
    const float* bih1 = (const float*)d_in[16];
    const float* bhh1 = (const float*)d_in[17];
    const float* W1 = (const float*)d_in[18];
    const float* b1 = (const float*)d_in[19];
    const float* W2 = (const float*)d_in[20];
    const float* b2 = (const float*)d_in[21];
    float* out = (float*)d_out;

    float* ws = (float*)d_ws;
    float* Wih0T = ws;                       // 5*384*512 = 983040
    float* Whh0T = Wih0T + 983040;           // 5*128*512 = 327680
    float* Wih1T = Whh0T + 327680;
    float* Whh1T = Wih1T + 327680;
    float* b0    = Whh1T + 327680;           // 2560
    float* b1c   = b0 + 2560;                // 2560
    float* X     = b1c + 2560;               // 25*640*384 = 6144000
    float* Gbuf  = X + 6144000;              // 25*640*512 = 8192000
    float* psum  = Gbuf + 8192000;           // 640

    hipMemsetAsync(psum, 0, NSEQ*sizeof(float), stream);
    transpose_w<<<3840,256,0,stream>>>(Wih0, Wih0T, GATES, IN0);
    transpose_w<<<1280,256,0,stream>>>(Whh0, Whh0T, GATES, DD);
    transpose_w<<<1280,256,0,stream>>>(Wih1, Wih1T, GATES, DD);
    transpose_w<<<1280,256,0,stream>>>(Whh1, Whh1T, GATES, DD);
    bias_prep<<<20,256,0,stream>>>(bih0,bhh0,bih1,bhh1,b0,b1c);
    gather_x<<<6000,256,0,stream>>>(uidx,tpath,ttype,trel,entity_emb,relation_emb,
                                    user_emb,news_emb,type_emb,X);
    gemm_ih0<<<1000,256,0,stream>>>(X, Wih0T, b0, Gbuf);
    lstm_kernel<<<NSEQ/LROWS*PP,256,0,stream>>>(Gbuf, Whh0T, Wih1T, Whh1T, b1c,
                                                W1, b1, W2, b2, psum);
    final_kernel<<<BB,64,0,stream>>>(cand, uidx, news_emb, user_emb, psum, out);
}

// Round 2
// 316.490 us; speedup vs baseline: 1.4135x; 1.4135x over previous
//
#include <hip/hip_runtime.h>
#include <math.h>

#define BB   128
#define CC   5
#define PP   5
#define LL   5
#define DD   128
#define NSEQ 640
#define GATES 512
#define IN0  384

typedef __attribute__((ext_vector_type(8))) short short8;   // 8 bf16 (4 VGPRs)
typedef __attribute__((ext_vector_type(4))) float f32x4;    // MFMA C/D

__device__ __forceinline__ float sigf(float x){ return 1.0f/(1.0f+__expf(-x)); }
__device__ __forceinline__ float tanhfast(float x){ return 1.0f - 2.0f/(__expf(2.0f*x)+1.0f); }

__device__ __forceinline__ unsigned short f2bf(float x){
    union { float f; unsigned u; } v; v.f = x;
    unsigned r = v.u + 0x7FFF + ((v.u >> 16) & 1);   // RNE
    return (unsigned short)(r >> 16);
}

// ---- prep: weights -> bf16 MFMA B-fragment layout; combined biases ----------
// Frag layout: F[((p*KT + kt)*32 + gt)*512 + lane*8 + j] =
//              bf16( W[p][g = gt*16 + (lane&15)][k = kt*32 + (lane>>4)*8 + j] )
// so a wave's global_load_dwordx4 at (base + lane*16B) IS the B fragment.
__global__ void prep_kernel(const float* __restrict__ Wih0, const float* __restrict__ Whh0,
                            const float* __restrict__ Wih1, const float* __restrict__ Whh1,
                            const float* __restrict__ bih0, const float* __restrict__ bhh0,
                            const float* __restrict__ bih1, const float* __restrict__ bhh1,
                            unsigned short* __restrict__ F0, unsigned short* __restrict__ F1,
                            unsigned short* __restrict__ F2, unsigned short* __restrict__ F3,
                            float* __restrict__ b0, float* __restrict__ b1c){
    int id = blockIdx.x*256 + threadIdx.x;
    const int NF0 = PP*12*32*64;     // 122880 fragments for Wih0 (K=384)
    const int NFH = PP*4*32*64;      // 40960 per hidden matrix (K=128)
    if (id < NF0 + 3*NFH){
        const float* src; unsigned short* dst; int K, KT, fid;
        if (id < NF0){ src = Wih0; dst = F0; K = IN0; KT = 12; fid = id; }
        else {
            int j = id - NF0; int m = j / NFH; fid = j % NFH; K = DD; KT = 4;
            src = (m==0)?Whh0:(m==1)?Wih1:Whh1;
            dst = (m==0)?F1:(m==1)?F2:F3;
        }
        int lane = fid & 63; int rem = fid >> 6;
        int gt = rem & 31; rem >>= 5;
        int kt = rem % KT; int p = rem / KT;
        int g  = gt*16 + (lane & 15);
        int k0 = kt*32 + (lane >> 4)*8;
        const float* s = src + (size_t)(p*GATES + g)*K + k0;
        float4 x0 = *(const float4*)s;
        float4 x1 = *(const float4*)(s+4);
        uint4 o;
        o.x = f2bf(x0.x) | ((unsigned)f2bf(x0.y)<<16);
        o.y = f2bf(x0.z) | ((unsigned)f2bf(x0.w)<<16);
        o.z = f2bf(x1.x) | ((unsigned)f2bf(x1.y)<<16);
        o.w = f2bf(x1.z) | ((unsigned)f2bf(x1.w)<<16);
        *(uint4*)(dst + (size_t)fid*8) = o;
    } else {
        int j = id - (NF0 + 3*NFH);
        if (j < PP*GATES) b0[j] = bih0[j] + bhh0[j];
        else if (j < 2*PP*GATES){ int q = j - PP*GATES; b1c[q] = bih1[q] + bhh1[q]; }
    }
}

// ---- gather + concat -> bf16 X[pt][n][384], only t<=p ------------------------
__global__ void gather_x(const int* __restrict__ user_index,
                         const int* __restrict__ tpath, const int* __restrict__ ttype,
                         const int* __restrict__ trel,
                         const float* __restrict__ entity_emb, const float* __restrict__ relation_emb,
                         const float* __restrict__ user_emb, const float* __restrict__ news_emb,
                         const float* __restrict__ type_emb,
                         unsigned short* __restrict__ X){
    int id = blockIdx.x*256 + threadIdx.x;       // 25*640*48 8-elt slots
    if (id >= PP*LL*NSEQ*48) return;
    int pt = id / (NSEQ*48); int rem = id % (NSEQ*48);
    int n = rem / 48, q = rem % 48;
    int p = pt / LL, t = pt % LL;
    if (t > p) return;
    int b = n / CC, c = n % CC;
    int u = user_index[b];
    int base = ((u*CC + c)*PP + p)*LL + t;
    int col = q*8;
    const float* s;
    if (q < 16){
        int ty = ttype[base]; int pi = tpath[base];
        const float* e = (ty==0)?user_emb:(ty==1)?news_emb:entity_emb;
        s = e + (size_t)pi*DD + col;
    } else if (q < 32){
        s = type_emb + (size_t)ttype[base]*DD + (col-128);
    } else {
        s = relation_emb + (size_t)trel[base]*DD + (col-256);
    }
    float4 x0 = *(const float4*)s, x1 = *(const float4*)(s+4);
    uint4 o;
    o.x = f2bf(x0.x) | ((unsigned)f2bf(x0.y)<<16);
    o.y = f2bf(x0.z) | ((unsigned)f2bf(x0.w)<<16);
    o.z = f2bf(x1.x) | ((unsigned)f2bf(x1.y)<<16);
    o.w = f2bf(x1.z) | ((unsigned)f2bf(x1.w)<<16);
    *(uint4*)(X + (size_t)(pt*NSEQ + n)*IN0 + col) = o;
}

// ---- MFMA GEMM: G0[pt][n][512] = X @ Wih0^T + b0  (fp32 out) ----------------
__global__ __launch_bounds__(256) void gemm_ih0_mfma(const unsigned short* __restrict__ X,
                                                     const unsigned short* __restrict__ F0,
                                                     const float* __restrict__ b0,
                                                     float* __restrict__ G0){
    int pt = blockIdx.x / 10;
    int nt = blockIdx.x % 10;
    int p = pt / LL, t = pt % LL;
    if (t > p) return;
    int lane = threadIdx.x & 63, w = threadIdx.x >> 6;
    int row0 = nt*64 + w*16;                  // wave owns 16 rows, all 512 cols
    f32x4 acc[32];
    #pragma unroll
    for (int i=0;i<32;i++) acc[i] = (f32x4)0.0f;
    int r = lane & 15, qd = lane >> 4;
    const unsigned short* Xb = X + ((size_t)(pt*NSEQ) + row0 + r)*IN0 + qd*8;
    const unsigned short* Fp = F0 + (size_t)p*12*32*512 + lane*8;
    for (int kt=0; kt<12; kt++){
        short8 a = *(const short8*)(Xb + kt*32);
        const unsigned short* fk = Fp + (size_t)kt*32*512;
        #pragma unroll
        for (int gt=0; gt<32; gt++){
            short8 bfr = *(const short8*)(fk + gt*512);
            acc[gt] = __builtin_amdgcn_mfma_f32_16x16x32_bf16(a, bfr, acc[gt], 0, 0, 0);
        }
    }
    const float* bp = b0 + p*GATES;
    float* Gb = G0 + ((size_t)(pt*NSEQ) + row0)*GATES;
    #pragma unroll
    for (int gt=0; gt<32; gt++){
        int col = gt*16 + r;
        float bias = bp[col];
        #pragma unroll
        for (int v=0; v<4; v++){
            Gb[(size_t)(qd*4+v)*GATES + col] = acc[gt][v] + bias;
        }
    }
}

// ---- fused 2-layer LSTM, MFMA recurrent GEMMs + scoring MLP -----------------
#define HPAD 136     // bf16 row stride (128 + 8) -> 16B-aligned rows, bank spread
#define GSW  516     // fp32 gate-stage row stride
__global__ __launch_bounds__(512) void lstm_mfma(
    const float* __restrict__ G0,
    const unsigned short* __restrict__ F1,   // Whh0 frags
    const unsigned short* __restrict__ F2,   // Wih1 frags
    const unsigned short* __restrict__ F3,   // Whh1 frags
    const float* __restrict__ b1c,
    const float* __restrict__ W1, const float* __restrict__ b1v,
    const float* __restrict__ W2, const float* __restrict__ b2v,
    float* __restrict__ psum){
    __shared__ float GS[16*GSW];             // 33.0 KB gate staging (fp32)
    __shared__ unsigned short h0T[16*HPAD];  // 4.35 KB h0 (bf16, A-frag rows)
    __shared__ unsigned short h1T[16*HPAD];
    __shared__ float h1f[16*132];            // 8.4 KB final h1 (fp32) for MLP
    __shared__ float mlpb[16*17];

    int p = blockIdx.x / 40, nt = blockIdx.x % 40;
    int n0 = nt*16;
    int tid = threadIdx.x;
    int lane = tid & 63, w = tid >> 6;       // 8 waves; wave w -> gate cols [64w,64w+64)
    int r16 = lane & 15, qd = lane >> 4;
    int cr = tid >> 5, cj = (tid & 31)*4;    // combine mapping: row cr, 4 hidden dims

    const unsigned short* F1p = F1 + (size_t)p*4*32*512 + lane*8;
    const unsigned short* F2p = F2 + (size_t)p*4*32*512 + lane*8;
    const unsigned short* F3p = F3 + (size_t)p*4*32*512 + lane*8;
    float c0s[4], c1s[4];
    float4 bi1 = *(const float4*)(b1c + p*GATES + cj);
    float4 bf1 = *(const float4*)(b1c + p*GATES + 128 + cj);
    float4 bg1 = *(const float4*)(b1c + p*GATES + 256 + cj);
    float4 bo1 = *(const float4*)(b1c + p*GATES + 384 + cj);

    for (int t=0; t<=p; t++){
        const float* g0row = G0 + ((size_t)((p*LL+t)*NSEQ) + n0 + cr)*GATES;
        // ---- layer 0 recurrent GEMM: h0 @ Whh0^T -> GS ----
        if (t > 0){
            f32x4 acc[4];
            #pragma unroll
            for (int i=0;i<4;i++) acc[i] = (f32x4)0.0f;
            #pragma unroll
            for (int kt=0; kt<4; kt++){
                short8 a = *(const short8*)(h0T + r16*HPAD + kt*32 + qd*8);
                #pragma unroll
                for (int i=0;i<4;i++){
                    short8 bfr = *(const short8*)(F1p + (size_t)(kt*32 + w*4 + i)*512);
                    acc[i] = __builtin_amdgcn_mfma_f32_16x16x32_bf16(a, bfr, acc[i], 0,0,0);
                }
            }
            #pragma unroll
            for (int i=0;i<4;i++)
                #pragma unroll
                for (int v=0;v<4;v++)
                    GS[(qd*4+v)*GSW + (w*4+i)*16 + r16] = acc[i][v];
            __syncthreads();
        }
        // ---- combine layer 0 ----
        {
            float4 gi = *(const float4*)(g0row + cj);
            float4 gf = *(const float4*)(g0row + 128 + cj);
            float4 gg = *(const float4*)(g0row + 256 + cj);
            float4 go = *(const float4*)(g0row + 384 + cj);
            if (t > 0){
                const float* gsr = GS + cr*GSW;
                float4 a0 = *(const float4*)(gsr + cj);
                float4 a1 = *(const float4*)(gsr + 128 + cj);
                float4 a2 = *(const float4*)(gsr + 256 + cj);
                float4 a3 = *(const float4*)(gsr + 384 + cj);
                gi.x+=a0.x; gi.y+=a0.y; gi.z+=a0.z; gi.w+=a0.w;
                gf.x+=a1.x; gf.y+=a1.y; gf.z+=a1.z; gf.w+=a1.w;
                gg.x+=a2.x; gg.y+=a2.y; gg.z+=a2.z; gg.w+=a2.w;
                go.x+=a3.x; go.y+=a3.y; go.z+=a3.z; go.w+=a3.w;
            }
            float hv[4];
            const float* pi = (const float*)&gi; const float* pf = (const float*)&gf;
            const float* pg = (const float*)&gg; const float* po = (const float*)&go;
            #pragma unroll
            for (int s=0;s<4;s++){
                float cp = (t>0) ? c0s[s] : 0.0f;
                float cc = sigf(pf[s])*cp + sigf(pi[s])*tanhfast(pg[s]);
                c0s[s] = cc;
                hv[s] = sigf(po[s])*tanhfast(cc);
            }
            uint2 pk;
            pk.x = f2bf(hv[0]) | ((unsigned)f2bf(hv[1])<<16);
            pk.y = f2bf(hv[2]) | ((unsigned)f2bf(hv[3])<<16);
            *(uint2*)(h0T + cr*HPAD + cj) = pk;
        }
        __syncthreads();
        // ---- layer 1 GEMM: h0 @ Wih1^T (+ h1 @ Whh1^T) -> GS ----
        {
            f32x4 acc[4];
            #pragma unroll
            for (int i=0;i<4;i++) acc[i] = (f32x4)0.0f;
            #pragma unroll
            for (int kt=0; kt<4; kt++){
                short8 a = *(const short8*)(h0T + r16*HPAD + kt*32 + qd*8);
                #pragma unroll
                for (int i=0;i<4;i++){
                    short8 bfr = *(const short8*)(F2p + (size_t)(kt*32 + w*4 + i)*512);
                    acc[i] = __builtin_amdgcn_mfma_f32_16x16x32_bf16(a, bfr, acc[i], 0,0,0);
                }
            }
            if (t > 0){
                #pragma unroll
                for (int kt=0; kt<4; kt++){
                    short8 a = *(const short8*)(h1T + r16*HPAD + kt*32 + qd*8);
                    #pragma unroll
                    for (int i=0;i<4;i++){
                        short8 bfr = *(const short8*)(F3p + (size_t)(kt*32 + w*4 + i)*512);
                        acc[i] = __builtin_amdgcn_mfma_f32_16x16x32_bf16(a, bfr, acc[i], 0,0,0);
                    }
                }
            }
            #pragma unroll
            for (int i=0;i<4;i++)
                #pragma unroll
                for (int v=0;v<4;v++)
                    GS[(qd*4+v)*GSW + (w*4+i)*16 + r16] = acc[i][v];
        }
        __syncthreads();
        // ---- combine layer 1 ----
        {
            const float* gsr = GS + cr*GSW;
            float4 gi = *(const float4*)(gsr + cj);
            float4 gf = *(const float4*)(gsr + 128 + cj);
            float4 gg = *(const float4*)(gsr + 256 + cj);
            float4 go = *(const float4*)(gsr + 384 + cj);
            gi.x+=bi1.x; gi.y+=bi1.y; gi.z+=bi1.z; gi.w+=bi1.w;
            gf.x+=bf1.x; gf.y+=bf1.y; gf.z+=bf1.z; gf.w+=bf1.w;
            gg.x+=bg1.x; gg.y+=bg1.y; gg.z+=bg1.z; gg.w+=bg1.w;
            go.x+=bo1.x; go.y+=bo1.y; go.z+=bo1.z; go.w+=bo1.w;
            float hv[4];
            const float* pi = (const float*)&gi; const float* pf = (const float*)&gf;
            const float* pg = (const float*)&gg; const float* po = (const float*)&go;
            #pragma unroll
            for (int s=0;s<4;s++){
                float cp = (t>0) ? c1s[s] : 0.0f;
                float cc = sigf(pf[s])*cp + sigf(pi[s])*tanhfast(pg[s]);
                c1s[s] = cc;
                hv[s] = sigf(po[s])*tanhfast(cc);
            }
            if (t < p){
                uint2 pk;
                pk.x = f2bf(hv[0]) | ((unsigned)f2bf(hv[1])<<16);
                pk.y = f2bf(hv[2]) | ((unsigned)f2bf(hv[3])<<16);
                *(uint2*)(h1T + cr*HPAD + cj) = pk;
            } else {
                float4 st; st.x=hv[0]; st.y=hv[1]; st.z=hv[2]; st.w=hv[3];
                *(float4*)(h1f + cr*132 + cj) = st;
            }
        }
        __syncthreads();
    }
    // ---- scoring MLP: sigmoid(relu(h1@W1^T+b1)@W2^T+b2), mean over paths ----
    if (tid < 256){
        int rr = tid & 15, hc = tid >> 4;
        const float* w1r = W1 + hc*DD;
        float acc = b1v[hc];
        #pragma unroll 4
        for (int k=0;k<DD;k++) acc = fmaf(h1f[rr*132 + k], w1r[k], acc);
        mlpb[hc*17 + rr] = fmaxf(acc, 0.0f);
    }
    __syncthreads();
    if (tid < 16){
        float s = b2v[0];
        #pragma unroll
        for (int h=0;h<16;h++) s = fmaf(mlpb[h*17 + tid], W2[h], s);
        atomicAdd(&psum[n0 + tid], 0.2f*sigf(s));
    }
}

// ---- final: emb_score + running mean (fp32 exact) ---------------------------
__global__ void final_kernel(const int* __restrict__ cand, const int* __restrict__ user_index,
                             const float* __restrict__ news_emb, const float* __restrict__ user_emb,
                             const float* __restrict__ psum, float* __restrict__ out){
    int b = blockIdx.x;
    int lane = threadIdx.x; // 64
    int u = user_index[b];
    const float* ue = user_emb + (size_t)u*DD;
    float cum = 0.0f;
    for (int c=0;c<CC;c++){
        int nb = cand[b*CC + c];
        const float* ne = news_emb + (size_t)nb*DD;
        float v = ne[lane]*ue[lane] + ne[lane+64]*ue[lane+64];
        #pragma unroll
        for (int off=32; off; off>>=1) v += __shfl_down(v, off, 64);
        if (lane == 0){
            cum += psum[b*CC + c];
            out[b*CC + c] = sigf(v) + cum/(float)(c+1);
        }
    }
}

extern "C" void kernel_launch(void* const* d_in, const int* in_sizes, int n_in,
                              void* d_out, int out_size, void* d_ws, size_t ws_size,
                              hipStream_t stream){
    const int* cand        = (const int*)d_in[0];
    const int* uidx        = (const int*)d_in[1];
    const int* tpath       = (const int*)d_in[2];
    const int* ttype       = (const int*)d_in[3];
    const int* trel        = (const int*)d_in[4];
    const float* entity_emb   = (const float*)d_in[5];
    const float* relation_emb = (const float*)d_in[6];
    const float* user_emb     = (const float*)d_in[7];
    const float* news_emb     = (const float*)d_in[8];
    const float* type_emb     = (const float*)d_in[9];
    const float* Wih0 = (const float*)d_in[10];
    const float* Whh0 = (const float*)d_in[11];
    const float* bih0 = (const float*)d_in[12];
    const float* bhh0 = (const float*)d_in[13];
    const float* Wih1 = (const float*)d_in[14];
    const float* Whh1 = (const float*)d_in[15];
    const float* bih1 = (const float*)d_in[16];
    const float* bhh1 = (const float*)d_in[17];
    const float* W1 = (const float*)d_in[18];
    const float* b1 = (const float*)d_in[19];
    const float* W2 = (const float*)d_in[20];
    const float* b2 = (const float*)d_in[21];
    float* out = (float*)d_out;

    char* ws = (char*)d_ws;
    unsigned short* F0 = (unsigned short*)ws;            ws += (size_t)PP*12*32*512*2;  // 1.97 MB
    unsigned short* F1 = (unsigned short*)ws;            ws += (size_t)PP*4*32*512*2;   // 655 KB
    unsigned short* F2 = (unsigned short*)ws;            ws += (size_t)PP*4*32*512*2;
    unsigned short* F3 = (unsigned short*)ws;            ws += (size_t)PP*4*32*512*2;
    float* b0  = (float*)ws;                             ws += PP*GATES*4;
    float* b1c = (float*)ws;                             ws += PP*GATES*4;
    unsigned short* X = (unsigned short*)ws;             ws += (size_t)PP*LL*NSEQ*IN0*2; // 12.3 MB
    float* G0 = (float*)ws;                              ws += (size_t)PP*LL*NSEQ*GATES*4; // 32.8 MB
    float* psum = (float*)ws;                            ws += NSEQ*4;

    hipMemsetAsync(psum, 0, NSEQ*sizeof(float), stream);
    prep_kernel<<<980,256,0,stream>>>(Wih0,Whh0,Wih1,Whh1,bih0,bhh0,bih1,bhh1,
                                      F0,F1,F2,F3,b0,b1c);
    gather_x<<<3000,256,0,stream>>>(uidx,tpath,ttype,trel,entity_emb,relation_emb,
                                    user_emb,news_emb,type_emb,X);
    gemm_ih0_mfma<<<250,256,0,stream>>>(X, F0, b0, G0);
    lstm_mfma<<<200,512,0,stream>>>(G0, F1, F2, F3, b1c, W1, b1, W2, b2, psum);
    final_kernel<<<BB,64,0,stream>>>(cand, uidx, news_emb, user_emb, psum, out);
}

// Round 3
// 240.006 us; speedup vs baseline: 1.8640x; 1.3187x over previous
//
#include <hip/hip_runtime.h>
#include <math.h>

#define BB   128
#define CC   5
#define PP   5
#define LL   5
#define DD   128
#define NSEQ 640
#define GATES 512
#define IN0  384
#define GSW  516
#define HPAD 136

typedef __attribute__((ext_vector_type(8))) short short8;   // 8 bf16
typedef __attribute__((ext_vector_type(4))) float f32x4;    // MFMA C/D

__device__ __forceinline__ float sigf(float x){ return 1.0f/(1.0f+__expf(-x)); }
__device__ __forceinline__ float tanhfast(float x){ return 1.0f - 2.0f/(__expf(2.0f*x)+1.0f); }

__device__ __forceinline__ unsigned short f2bf(float x){
    union { float f; unsigned u; } v; v.f = x;
    unsigned r = v.u + 0x7FFF + ((v.u >> 16) & 1);   // RNE
    return (unsigned short)(r >> 16);
}

// ---- prep: weights -> bf16 MFMA B-fragment layout; combined biases ----------
// F[((p*KT + kt)*32 + gt)*512 + lane*8 + j] = bf16( W[p][gt*16+(lane&15)][kt*32+(lane>>4)*8+j] )
__global__ void prep_kernel(const float* __restrict__ Wih0, const float* __restrict__ Whh0,
                            const float* __restrict__ Wih1, const float* __restrict__ Whh1,
                            const float* __restrict__ bih0, const float* __restrict__ bhh0,
                            const float* __restrict__ bih1, const float* __restrict__ bhh1,
                            unsigned short* __restrict__ F0, unsigned short* __restrict__ F1,
                            unsigned short* __restrict__ F2, unsigned short* __restrict__ F3,
                            float* __restrict__ b0, float* __restrict__ b1c){
    int id = blockIdx.x*256 + threadIdx.x;
    const int NF0 = PP*12*32*64;
    const int NFH = PP*4*32*64;
    if (id < NF0 + 3*NFH){
        const float* src; unsigned short* dst; int K, KT, fid;
        if (id < NF0){ src = Wih0; dst = F0; K = IN0; KT = 12; fid = id; }
        else {
            int j = id - NF0; int m = j / NFH; fid = j % NFH; K = DD; KT = 4;
            src = (m==0)?Whh0:(m==1)?Wih1:Whh1;
            dst = (m==0)?F1:(m==1)?F2:F3;
        }
        int lane = fid & 63; int rem = fid >> 6;
        int gt = rem & 31; rem >>= 5;
        int kt = rem % KT; int p = rem / KT;
        int g  = gt*16 + (lane & 15);
        int k0 = kt*32 + (lane >> 4)*8;
        const float* s = src + (size_t)(p*GATES + g)*K + k0;
        float4 x0 = *(const float4*)s;
        float4 x1 = *(const float4*)(s+4);
        uint4 o;
        o.x = f2bf(x0.x) | ((unsigned)f2bf(x0.y)<<16);
        o.y = f2bf(x0.z) | ((unsigned)f2bf(x0.w)<<16);
        o.z = f2bf(x1.x) | ((unsigned)f2bf(x1.y)<<16);
        o.w = f2bf(x1.z) | ((unsigned)f2bf(x1.w)<<16);
        *(uint4*)(dst + (size_t)fid*8) = o;
    } else {
        int j = id - (NF0 + 3*NFH);
        if (j < PP*GATES) b0[j] = bih0[j] + bhh0[j];
        else if (j < 2*PP*GATES){ int q = j - PP*GATES; b1c[q] = bih1[q] + bhh1[q]; }
    }
}

// ---- gather + concat -> bf16 X[pt][n][384], only t<=p ------------------------
__global__ void gather_x(const int* __restrict__ user_index,
                         const int* __restrict__ tpath, const int* __restrict__ ttype,
                         const int* __restrict__ trel,
                         const float* __restrict__ entity_emb, const float* __restrict__ relation_emb,
                         const float* __restrict__ user_emb, const float* __restrict__ news_emb,
                         const float* __restrict__ type_emb,
                         unsigned short* __restrict__ X){
    int id = blockIdx.x*256 + threadIdx.x;
    if (id >= PP*LL*NSEQ*48) return;
    int pt = id / (NSEQ*48); int rem = id % (NSEQ*48);
    int n = rem / 48, q = rem % 48;
    int p = pt / LL, t = pt % LL;
    if (t > p) return;
    int b = n / CC, c = n % CC;
    int u = user_index[b];
    int base = ((u*CC + c)*PP + p)*LL + t;
    int col = q*8;
    const float* s;
    if (q < 16){
        int ty = ttype[base]; int pi = tpath[base];
        const float* e = (ty==0)?user_emb:(ty==1)?news_emb:entity_emb;
        s = e + (size_t)pi*DD + col;
    } else if (q < 32){
        s = type_emb + (size_t)ttype[base]*DD + (col-128);
    } else {
        s = relation_emb + (size_t)trel[base]*DD + (col-256);
    }
    float4 x0 = *(const float4*)s, x1 = *(const float4*)(s+4);
    uint4 o;
    o.x = f2bf(x0.x) | ((unsigned)f2bf(x0.y)<<16);
    o.y = f2bf(x0.z) | ((unsigned)f2bf(x0.w)<<16);
    o.z = f2bf(x1.x) | ((unsigned)f2bf(x1.y)<<16);
    o.w = f2bf(x1.z) | ((unsigned)f2bf(x1.w)<<16);
    *(uint4*)(X + (size_t)(pt*NSEQ + n)*IN0 + col) = o;
}

// ---- tiled MFMA GEMM: G0c (C-frag layout) = X @ Wih0^T ----------------------
// grid: 25 pt x 10 m64 x 8 nch. Block 256 thr: 64 rows x 64 cols, B staged in LDS.
// G0c[tile16][gt][lane][4], tile16 = pt*40 + row/16
__global__ __launch_bounds__(256) void gemm_ih0_v3(const unsigned short* __restrict__ X,
                                                   const unsigned short* __restrict__ F0,
                                                   float* __restrict__ G0c){
    __shared__ unsigned short Bs[12*4*512];   // 48 KB
    int bx = blockIdx.x;
    int nch = bx & 7;
    int m64 = (bx >> 3) % 10;
    int pt  = bx / 80;
    int p = pt / LL, t = pt % LL;
    if (t > p) return;
    int tid = threadIdx.x, lane = tid & 63, w = tid >> 6;
    int r16 = lane & 15, qd = lane >> 4;

    const unsigned short* Fp = F0 + (((size_t)p*12)*32 + nch*4)*512;
    uint4 breg[12];
    #pragma unroll
    for (int j=0;j<12;j++)
        breg[j] = *(const uint4*)(Fp + (size_t)j*32*512 + tid*8);
    #pragma unroll
    for (int j=0;j<12;j++)
        *(uint4*)(Bs + j*2048 + tid*8) = breg[j];
    __syncthreads();

    f32x4 acc[4];
    #pragma unroll
    for (int i=0;i<4;i++) acc[i] = (f32x4)0.0f;
    const unsigned short* Xb = X + ((size_t)pt*NSEQ + m64*64 + w*16 + r16)*IN0 + qd*8;
    #pragma unroll
    for (int kt=0; kt<12; kt++){
        short8 a = *(const short8*)(Xb + kt*32);
        #pragma unroll
        for (int i=0;i<4;i++){
            short8 bfr = *(const short8*)(Bs + (kt*4+i)*512 + lane*8);
            acc[i] = __builtin_amdgcn_mfma_f32_16x16x32_bf16(a, bfr, acc[i], 0,0,0);
        }
    }
    int tile16 = pt*40 + m64*4 + w;
    float* dst = G0c + (((size_t)tile16*32 + nch*4)*64 + lane)*4;
    #pragma unroll
    for (int i=0;i<4;i++)
        *(f32x4*)(dst + (size_t)i*256) = acc[i];
}

// ---- fused 2-layer LSTM: reg-prefetched G0 slabs, reg-cached L1 weights -----
__global__ __launch_bounds__(512) void lstm_v3(
    const float* __restrict__ G0c,
    const unsigned short* __restrict__ F1,   // Whh0 frags (streamed)
    const unsigned short* __restrict__ F2,   // Wih1 frags (reg-cached)
    const unsigned short* __restrict__ F3,   // Whh1 frags (reg-cached)
    const float* __restrict__ b0, const float* __restrict__ b1c,
    const float* __restrict__ W1, const float* __restrict__ b1v,
    const float* __restrict__ W2, const float* __restrict__ b2v,
    float* __restrict__ psum){
    __shared__ float GS[16*GSW];             // 33 KB preact staging
    __shared__ unsigned short h0T[16*HPAD];  // 4.35 KB
    __shared__ unsigned short h1T[16*HPAD];
    __shared__ float h1f[16*132];            // 8.4 KB
    __shared__ float mlpb[16*17];

    int p = blockIdx.x / 40, nt = blockIdx.x % 40;
    int n0 = nt*16;
    int tid = threadIdx.x;
    int lane = tid & 63, w = tid >> 6;       // 8 waves; wave w -> gate cols [64w,64w+64)
    int r16 = lane & 15, qd = lane >> 4;
    int cr = tid >> 5, cj = (tid & 31)*4;

    // zero h state
    for (int i = tid; i < 16*HPAD/2; i += 512){
        ((unsigned*)h0T)[i] = 0u; ((unsigned*)h1T)[i] = 0u;
    }

    // reg-cache layer-1 weight fragments (wave's 4-gt slice): 32 frags = 128 VGPRs
    short8 f2r[16], f3r[16];
    {
        const unsigned short* F2p = F2 + (size_t)p*4*32*512 + lane*8;
        const unsigned short* F3p = F3 + (size_t)p*4*32*512 + lane*8;
        #pragma unroll
        for (int kt=0; kt<4; kt++)
            #pragma unroll
            for (int i=0;i<4;i++){
                f2r[kt*4+i] = *(const short8*)(F2p + (size_t)(kt*32 + w*4+i)*512);
                f3r[kt*4+i] = *(const short8*)(F3p + (size_t)(kt*32 + w*4+i)*512);
            }
    }
    float bL0[4], bL1[4];
    #pragma unroll
    for (int i=0;i<4;i++){
        int col = (w*4+i)*16 + r16;
        bL0[i] = b0[p*GATES + col];
        bL1[i] = b1c[p*GATES + col];
    }
    const unsigned short* F1p = F1 + (size_t)p*4*32*512 + lane*8;

    // prefetch slab t=0 into regs (C-layout: exactly this wave's acc lanes)
    f32x4 pf[4];
    {
        const float* slab = G0c + (size_t)((p*LL + 0)*40 + nt)*8192;
        #pragma unroll
        for (int i=0;i<4;i++) pf[i] = *(const f32x4*)(slab + ((w*4+i)*64 + lane)*4);
    }
    float c0s[4] = {0,0,0,0}, c1s[4] = {0,0,0,0};
    __syncthreads();

    for (int t=0; t<=p; t++){
        // ---- (A) layer0 preact: acc = G0 slab + bias (+ h0 @ Whh0) ----
        f32x4 acc[4];
        #pragma unroll
        for (int i=0;i<4;i++){
            f32x4 a = pf[i]; float bb = bL0[i];
            a[0]+=bb; a[1]+=bb; a[2]+=bb; a[3]+=bb;
            acc[i] = a;
        }
        if (t < p){   // prefetch next slab; full iteration of latency slack
            const float* ns = G0c + (size_t)((p*LL + t + 1)*40 + nt)*8192;
            #pragma unroll
            for (int i=0;i<4;i++) pf[i] = *(const f32x4*)(ns + ((w*4+i)*64 + lane)*4);
        }
        if (t > 0){
            #pragma unroll
            for (int kt=0; kt<4; kt++){
                short8 a = *(const short8*)(h0T + r16*HPAD + kt*32 + qd*8);
                #pragma unroll
                for (int i=0;i<4;i++){
                    short8 bfr = *(const short8*)(F1p + (size_t)(kt*32 + w*4+i)*512);
                    acc[i] = __builtin_amdgcn_mfma_f32_16x16x32_bf16(a, bfr, acc[i], 0,0,0);
                }
            }
        }
        #pragma unroll
        for (int i=0;i<4;i++)
            #pragma unroll
            for (int v=0;v<4;v++)
                GS[(qd*4+v)*GSW + (w*4+i)*16 + r16] = acc[i][v];
        __syncthreads();
        // ---- (B) combine layer 0 ----
        {
            const float* gsr = GS + cr*GSW;
            float4 gi = *(const float4*)(gsr + cj);
            float4 gf = *(const float4*)(gsr + 128 + cj);
            float4 gg = *(const float4*)(gsr + 256 + cj);
            float4 go = *(const float4*)(gsr + 384 + cj);
            float hv[4];
            const float* pi = (const float*)&gi; const float* pfv = (const float*)&gf;
            const float* pg = (const float*)&gg; const float* po = (const float*)&go;
            #pragma unroll
            for (int s=0;s<4;s++){
                float cc = sigf(pfv[s])*c0s[s] + sigf(pi[s])*tanhfast(pg[s]);
                c0s[s] = cc;
                hv[s] = sigf(po[s])*tanhfast(cc);
            }
            uint2 pk;
            pk.x = f2bf(hv[0]) | ((unsigned)f2bf(hv[1])<<16);
            pk.y = f2bf(hv[2]) | ((unsigned)f2bf(hv[3])<<16);
            *(uint2*)(h0T + cr*HPAD + cj) = pk;
        }
        __syncthreads();
        // ---- (C) layer1 preact: bias + h0@Wih1 (+ h1@Whh1), weights in regs ----
        #pragma unroll
        for (int i=0;i<4;i++){
            float bb = bL1[i];
            f32x4 a; a[0]=bb; a[1]=bb; a[2]=bb; a[3]=bb;
            acc[i] = a;
        }
        #pragma unroll
        for (int kt=0; kt<4; kt++){
            short8 a = *(const short8*)(h0T + r16*HPAD + kt*32 + qd*8);
            #pragma unroll
            for (int i=0;i<4;i++)
                acc[i] = __builtin_amdgcn_mfma_f32_16x16x32_bf16(a, f2r[kt*4+i], acc[i], 0,0,0);
        }
        if (t > 0){
            #pragma unroll
            for (int kt=0; kt<4; kt++){
                short8 a = *(const short8*)(h1T + r16*HPAD + kt*32 + qd*8);
                #pragma unroll
                for (int i=0;i<4;i++)
                    acc[i] = __builtin_amdgcn_mfma_f32_16x16x32_bf16(a, f3r[kt*4+i], acc[i], 0,0,0);
            }
        }
        #pragma unroll
        for (int i=0;i<4;i++)
            #pragma unroll
            for (int v=0;v<4;v++)
                GS[(qd*4+v)*GSW + (w*4+i)*16 + r16] = acc[i][v];
        __syncthreads();
        // ---- (D) combine layer 1 ----
        {
            const float* gsr = GS + cr*GSW;
            float4 gi = *(const float4*)(gsr + cj);
            float4 gf = *(const float4*)(gsr + 128 + cj);
            float4 gg = *(const float4*)(gsr + 256 + cj);
            float4 go = *(const float4*)(gsr + 384 + cj);
            float hv[4];
            const float* pi = (const float*)&gi; const float* pfv = (const float*)&gf;
            const float* pg = (const float*)&gg; const float* po = (const float*)&go;
            #pragma unroll
            for (int s=0;s<4;s++){
                float cc = sigf(pfv[s])*c1s[s] + sigf(pi[s])*tanhfast(pg[s]);
                c1s[s] = cc;
                hv[s] = sigf(po[s])*tanhfast(cc);
            }
            if (t < p){
                uint2 pk;
                pk.x = f2bf(hv[0]) | ((unsigned)f2bf(hv[1])<<16);
                pk.y = f2bf(hv[2]) | ((unsigned)f2bf(hv[3])<<16);
                *(uint2*)(h1T + cr*HPAD + cj) = pk;
            } else {
                float4 st; st.x=hv[0]; st.y=hv[1]; st.z=hv[2]; st.w=hv[3];
                *(float4*)(h1f + cr*132 + cj) = st;
            }
        }
        __syncthreads();
    }
    // ---- scoring MLP: sigmoid(relu(h1@W1^T+b1)@W2^T+b2), mean over paths ----
    if (tid < 256){
        int rr = tid & 15, hc = tid >> 4;
        const float* w1r = W1 + hc*DD;
        float acc = b1v[hc];
        #pragma unroll 4
        for (int k=0;k<DD;k++) acc = fmaf(h1f[rr*132 + k], w1r[k], acc);
        mlpb[hc*17 + rr] = fmaxf(acc, 0.0f);
    }
    __syncthreads();
    if (tid < 16){
        float s = b2v[0];
        #pragma unroll
        for (int h=0;h<16;h++) s = fmaf(mlpb[h*17 + tid], W2[h], s);
        atomicAdd(&psum[n0 + tid], 0.2f*sigf(s));
    }
}

// ---- final: emb_score + running mean (fp32 exact) ---------------------------
__global__ void final_kernel(const int* __restrict__ cand, const int* __restrict__ user_index,
                             const float* __restrict__ news_emb, const float* __restrict__ user_emb,
                             const float* __restrict__ psum, float* __restrict__ out){
    int b = blockIdx.x;
    int lane = threadIdx.x; // 64
    int u = user_index[b];
    const float* ue = user_emb + (size_t)u*DD;
    float cum = 0.0f;
    for (int c=0;c<CC;c++){
        int nb = cand[b*CC + c];
        const float* ne = news_emb + (size_t)nb*DD;
        float v = ne[lane]*ue[lane] + ne[lane+64]*ue[lane+64];
        #pragma unroll
        for (int off=32; off; off>>=1) v += __shfl_down(v, off, 64);
        if (lane == 0){
            cum += psum[b*CC + c];
            out[b*CC + c] = sigf(v) + cum/(float)(c+1);
        }
    }
}

extern "C" void kernel_launch(void* const* d_in, const int* in_sizes, int n_in,
                              void* d_out, int out_size, void* d_ws, size_t ws_size,
                              hipStream_t stream){
    const int* cand        = (const int*)d_in[0];
    const int* uidx        = (const int*)d_in[1];
    const int* tpath       = (const int*)d_in[2];
    const int* ttype       = (const int*)d_in[3];
    const int* trel        = (const int*)d_in[4];
    const float* entity_emb   = (const float*)d_in[5];
    const float* relation_emb = (const float*)d_in[6];
    const float* user_emb     = (const float*)d_in[7];
    const float* news_emb     = (const float*)d_in[8];
    const float* type_emb     = (const float*)d_in[9];
    const float* Wih0 = (const float*)d_in[10];
    const float* Whh0 = (const float*)d_in[11];
    const float* bih0 = (const float*)d_in[12];
    const float* bhh0 = (const float*)d_in[13];
    const float* Wih1 = (const float*)d_in[14];
    const float* Whh1 = (const float*)d_in[15];
    const float* bih1 = (const float*)d_in[16];
    const float* bhh1 = (const float*)d_in[17];
    const float* W1 = (const float*)d_in[18];
    const float* b1 = (const float*)d_in[19];
    const float* W2 = (const float*)d_in[20];
    const float* b2 = (const float*)d_in[21];
    float* out = (float*)d_out;

    char* ws = (char*)d_ws;
    unsigned short* F0 = (unsigned short*)ws;  ws += (size_t)PP*12*32*512*2;   // 1.97 MB
    unsigned short* F1 = (unsigned short*)ws;  ws += (size_t)PP*4*32*512*2;
    unsigned short* F2 = (unsigned short*)ws;  ws += (size_t)PP*4*32*512*2;
    unsigned short* F3 = (unsigned short*)ws;  ws += (size_t)PP*4*32*512*2;
    float* b0  = (float*)ws;                   ws += PP*GATES*4;
    float* b1c = (float*)ws;                   ws += PP*GATES*4;
    unsigned short* X = (unsigned short*)ws;   ws += (size_t)PP*LL*NSEQ*IN0*2; // 12.3 MB
    float* G0c = (float*)ws;                   ws += (size_t)PP*LL*NSEQ*GATES*4; // 32.8 MB
    float* psum = (float*)ws;                  ws += NSEQ*4;

    hipMemsetAsync(psum, 0, NSEQ*sizeof(float), stream);
    prep_kernel<<<980,256,0,stream>>>(Wih0,Whh0,Wih1,Whh1,bih0,bhh0,bih1,bhh1,
                                      F0,F1,F2,F3,b0,b1c);
    gather_x<<<3000,256,0,stream>>>(uidx,tpath,ttype,trel,entity_emb,relation_emb,
                                    user_emb,news_emb,type_emb,X);
    gemm_ih0_v3<<<2000,256,0,stream>>>(X, F0, G0c);
    lstm_v3<<<200,512,0,stream>>>(G0c, F1, F2, F3, b0, b1c, W1, b1, W2, b2, psum);
    final_kernel<<<BB,64,0,stream>>>(cand, uidx, news_emb, user_emb, psum, out);
}